// Round 3
// baseline (141.123 us; speedup 1.0000x reference)
//
#include <hip/hip_runtime.h>
#include <math.h>

// ---- problem constants (derived from reference) ----
// Point-anchors => IoU==0 => only anchor 0 positive per (b,level), gt idx 31.
// num_pos == 192 deterministically.
#define NUM_POS_F 192.0f
#define WING_W_F 10.0f
#define WING_EPS_F 2.0f
// WING_C = 10 - 10*ln(6)
#define WING_C_F (-7.917594692280550f)
#define CLS_W_F 1.0f
#define REG_W_F 2.0f
#define KPT_W_F 1.5f

#define NCLS0 1638400   // 64*160*160
#define NCLS1 409600    // 64*80*80
#define NCLS2 102400    // 64*40*40
#define N0_4 (NCLS0/4)  // 409600
#define N1_4 (NCLS1/4)  // 102400
#define N2_4 (NCLS2/4)  // 25600

// Streaming blocks sized so EVERY thread loads exactly 2 float4s (no loop, ILP-2):
// NB0*256*2 = 409600, NB1*256*2 = 102400, NB2*256*2 = 25600. Zero raggedness.
#define NB0 800
#define NB1 200
#define NB2 50
#define GRID_STREAM (NB0 + NB1 + NB2)   // 1050
#define GRID_MAIN   (GRID_STREAM + 1)   // +1 block for the 192 positives (runs
                                        // concurrently; its scattered-load latency
                                        // hides under the streaming blocks)
// ws layout: [0..1050) per-block cls partials; [1050]=cls_corr, [1051]=reg_sum,
// [1052]=kpt_sum from the positives block. Disjoint plain stores; kernel boundary
// guarantees visibility to finalize.
// NOTE (prior session): do NOT fuse via cooperative grid.sync — measured +55 µs
// (device-scope arrive/wait across 8 XCDs). Self-resetting atomic counters are
// unsafe under harness ws re-poison. Keep 2 kernels.

// fast branchless focal(target=0): e=exp(-|x|); t=1+e; sig=(x>=0?1:e)/t;
// softplus=max(x,0)+log(t); focal0 = 0.75*sig^2*softplus. 1 exp + 1 log + 1 rcp.
__device__ __forceinline__ float focal0_fast(float x) {
    float e  = __expf(-fabsf(x));
    float t  = 1.0f + e;
    float r  = __builtin_amdgcn_rcpf(t);
    float sp = fmaxf(x, 0.0f) + __logf(t);
    float p  = (x >= 0.0f) ? r : e * r;
    return 0.75f * p * p * sp;
}
// focal(target=1) = 0.25 * sigmoid(-x)^2 * softplus(-x)  (192 uses only)
__device__ __forceinline__ float focal1_fast(float x) {
    float e  = __expf(-fabsf(x));
    float t  = 1.0f + e;
    float r  = __builtin_amdgcn_rcpf(t);
    float sp = fmaxf(-x, 0.0f) + __logf(t);
    float q  = (x <= 0.0f) ? r : e * r;   // sigmoid(-x)
    return 0.25f * q * q * sp;
}

__device__ __forceinline__ void block_reduce3(float& a, float& b, float& c) {
    #pragma unroll
    for (int off = 32; off > 0; off >>= 1) {
        a += __shfl_down(a, off);
        b += __shfl_down(b, off);
        c += __shfl_down(c, off);
    }
    __shared__ float s_red[4][3];
    const int wave = threadIdx.x >> 6;
    const int lane = threadIdx.x & 63;
    if (lane == 0) { s_red[wave][0] = a; s_red[wave][1] = b; s_red[wave][2] = c; }
    __syncthreads();
    if (threadIdx.x == 0) {
        a = s_red[0][0] + s_red[1][0] + s_red[2][0] + s_red[3][0];
        b = s_red[0][1] + s_red[1][1] + s_red[2][1] + s_red[3][1];
        c = s_red[0][2] + s_red[1][2] + s_red[2][2] + s_red[3][2];
    }
}

// ---- kernel 1: streaming focal(target=0) + concurrent positives block ----
__global__ __launch_bounds__(256) void det_loss_partials(
    const float* __restrict__ cls0, const float* __restrict__ cls1, const float* __restrict__ cls2,
    const float* __restrict__ reg0, const float* __restrict__ reg1, const float* __restrict__ reg2,
    const float* __restrict__ kpt0, const float* __restrict__ kpt1, const float* __restrict__ kpt2,
    const float* __restrict__ gt, float* __restrict__ ws)
{
    const unsigned bid = blockIdx.x;
    const unsigned tid = threadIdx.x;

    if (bid < GRID_STREAM) {
        const float4* src; unsigned lbid;
        if (bid < NB0)            { src = (const float4*)cls0; lbid = bid; }
        else if (bid < NB0 + NB1) { src = (const float4*)cls1; lbid = bid - NB0; }
        else                      { src = (const float4*)cls2; lbid = bid - NB0 - NB1; }

        // two independent coalesced float4 loads per thread (ILP-2, exact cover)
        const unsigned base = lbid * 512u + tid;
        float4 v0 = src[base];
        float4 v1 = src[base + 256u];
        float s = focal0_fast(v0.x) + focal0_fast(v0.y) + focal0_fast(v0.z) + focal0_fast(v0.w)
                + focal0_fast(v1.x) + focal0_fast(v1.y) + focal0_fast(v1.z) + focal0_fast(v1.w);

        #pragma unroll
        for (int off = 32; off > 0; off >>= 1) s += __shfl_down(s, off);
        __shared__ float sr[4];
        if ((tid & 63u) == 0u) sr[tid >> 6] = s;
        __syncthreads();
        if (tid == 0)
            ws[bid] = sr[0] + sr[1] + sr[2] + sr[3];
    } else {
        // ---- positives block: 192 scattered gathers, overlapped with streaming ----
        float cls_c = 0.0f, reg_s = 0.0f, kpt_s = 0.0f;
        if (tid < 192) {
            int level = tid >> 6;
            int b     = tid & 63;
            const float *cls, *reg, *kpt; int A; float s;
            if (level == 0)      { cls = cls0; reg = reg0; kpt = kpt0; A = 25600; s = 8.0f;  }
            else if (level == 1) { cls = cls1; reg = reg1; kpt = kpt1; A = 6400;  s = 16.0f; }
            else                 { cls = cls2; reg = reg2; kpt = kpt2; A = 1600;  s = 32.0f; }

            // cls: flip target 0 -> 1 at (b, 0, 0)
            float x = cls[(size_t)b * A];
            cls_c += focal1_fast(x) - focal0_fast(x);

            // reg: decode pred at anchor 0 (ax=ay=s/2); target box == gt[b][31]
            const float* rb = reg + (size_t)b * 4 * A;
            float t0 = rb[0], t1 = rb[(size_t)A], t2 = rb[(size_t)2*A], t3 = rb[(size_t)3*A];
            float half = 0.5f * s;
            float pw = __expf(t2), ph = __expf(t3);
            float px1 = t0 * s + half, py1 = t1 * s + half;
            float px2 = px1 + pw,      py2 = py1 + ph;
            const float* g = gt + (size_t)b * 128 + 31 * 4;
            float gx1 = g[0], gy1 = g[1], gx2 = g[2], gy2 = g[3];
            float tw = gx2 - gx1, th = gy2 - gy1;
            float pcx = 0.5f * (px1 + px2), pcy = 0.5f * (py1 + py2);
            float tcx = 0.5f * (gx1 + gx2), tcy = 0.5f * (gy1 + gy2);
            float iw = fmaxf(fminf(px2, gx2) - fmaxf(px1, gx1), 0.0f);
            float ih = fmaxf(fminf(py2, gy2) - fmaxf(py1, gy1), 0.0f);
            float inter = iw * ih;
            float uni = pw * ph + tw * th - inter;
            float iou = inter / fmaxf(uni, 1e-7f);
            float cw  = fmaxf(px2, gx2) - fminf(px1, gx1);
            float chh = fmaxf(py2, gy2) - fminf(py1, gy1);
            float dx = pcx - tcx, dy = pcy - tcy;
            float rho = dx * dx + dy * dy;
            float c2 = cw * cw + chh * chh;
            const float KPI = 4.0f / (float)(M_PI * M_PI);
            float dv = atanf(tw / fmaxf(th, 1e-7f)) - atanf(pw / fmaxf(ph, 1e-7f));
            float v = KPI * dv * dv;
            float al = v / (1.0f - iou + v + 1e-7f);
            float ciou = iou - rho / fmaxf(c2, 1e-7f) - al * v;
            reg_s += 1.0f - ciou;

            // kpt: wing(|pred|) over 10 channels at anchor 0
            const float* kb = kpt + (size_t)b * 10 * A;
            #pragma unroll
            for (int c = 0; c < 10; ++c) {
                float a = fabsf(kb[(size_t)c * A]);
                kpt_s += (a < WING_W_F) ? WING_W_F * __logf(1.0f + a * (1.0f / WING_EPS_F))
                                        : (a - WING_C_F);
            }
        }
        block_reduce3(cls_c, reg_s, kpt_s);
        if (tid == 0) {
            ws[GRID_STREAM]     = cls_c;
            ws[GRID_STREAM + 1] = reg_s;
            ws[GRID_STREAM + 2] = kpt_s;
        }
    }
}

// ---- kernel 2: pure ws reduction (coalesced, no scattered HBM reads) ----
__global__ __launch_bounds__(256) void det_loss_finalize(
    const float* __restrict__ ws, float* __restrict__ out)
{
    const unsigned tid = threadIdx.x;
    float cls_sum = 0.0f;
    for (unsigned j = tid; j < GRID_STREAM; j += 256u)
        cls_sum += ws[j];

    #pragma unroll
    for (int off = 32; off > 0; off >>= 1) cls_sum += __shfl_down(cls_sum, off);
    __shared__ float sr[4];
    if ((tid & 63u) == 0u) sr[tid >> 6] = cls_sum;
    __syncthreads();
    if (tid == 0) {
        float cls_total = sr[0] + sr[1] + sr[2] + sr[3] + ws[GRID_STREAM];
        float reg_total = ws[GRID_STREAM + 1];
        float kpt_total = ws[GRID_STREAM + 2];
        float loss_cls = cls_total * (1.0f / NUM_POS_F);
        float loss_reg = reg_total * (1.0f / NUM_POS_F);
        float loss_kpt = kpt_total * (1.0f / NUM_POS_F);
        out[0] = CLS_W_F * loss_cls + REG_W_F * loss_reg + KPT_W_F * loss_kpt;
        out[1] = loss_cls;
        out[2] = loss_reg;
        out[3] = loss_kpt;
    }
}

extern "C" void kernel_launch(void* const* d_in, const int* in_sizes, int n_in,
                              void* d_out, int out_size, void* d_ws, size_t ws_size,
                              hipStream_t stream) {
    const float* cls0 = (const float*)d_in[0];
    const float* reg0 = (const float*)d_in[1];
    const float* kpt0 = (const float*)d_in[2];
    const float* cls1 = (const float*)d_in[3];
    const float* reg1 = (const float*)d_in[4];
    const float* kpt1 = (const float*)d_in[5];
    const float* cls2 = (const float*)d_in[6];
    const float* reg2 = (const float*)d_in[7];
    const float* kpt2 = (const float*)d_in[8];
    const float* gt   = (const float*)d_in[9];
    float* ws  = (float*)d_ws;
    float* out = (float*)d_out;

    hipLaunchKernelGGL(det_loss_partials, dim3(GRID_MAIN), dim3(256), 0, stream,
                       cls0, cls1, cls2, reg0, reg1, reg2,
                       kpt0, kpt1, kpt2, gt, ws);
    hipLaunchKernelGGL(det_loss_finalize, dim3(1), dim3(256), 0, stream,
                       ws, out);
}